// Round 20
// baseline (177.718 us; speedup 1.0000x reference)
//
#include <hip/hip_runtime.h>
#include <hip/hip_fp16.h>

typedef unsigned short u16;
typedef unsigned int   u32;
typedef _Float16 f16;
typedef __attribute__((ext_vector_type(8))) f16 f16x8;
typedef __attribute__((ext_vector_type(2))) __fp16 fp16x2;   // cvt_pkrtz return type
typedef __attribute__((ext_vector_type(4))) float f32x4;

#define B_SZ  2
#define L_SEQ 1024
#define D_EMB 768
#define KF    16
#define MDIM  (B_SZ * L_SEQ)   // 2048 GEMM rows
#define KROW  (KF * D_EMB)     // 12288 per-row A length
#define MELEM ((size_t)KF * D_EMB * D_EMB)   // 9,437,184 per M matrix
#define PT2   8192              // 64x128 partial tile elems

// ---- async global->LDS, 16B per lane (linear LDS dest: wave base + lane*16) ----
__device__ __forceinline__ void gload16(const void* g, void* l) {
    __builtin_amdgcn_global_load_lds(
        (const __attribute__((address_space(1))) u32*)g,
        (__attribute__((address_space(3))) u32*)l, 16, 0, 0);
}

// counted vmcnt waits (T4): literal-only, memory-clobbered so staging/ds ops
// cannot be reordered across them by the compiler.
#define VMCNT6() asm volatile("s_waitcnt vmcnt(6)" ::: "memory")
#define VMCNT0() asm volatile("s_waitcnt vmcnt(0)" ::: "memory")

// =====================================================================
// Setup (fused, round-13 verified): blocks 0..383 transpose x -> xT
// (pre-swizzled); blocks 384..639 build the PLUS-ONLY Toeplitz tile
// table (64x64 tiles, pre-swizzled).
// =====================================================================
__global__ __launch_bounds__(256) void stu_setup(const float* __restrict__ x,
                                                 const float* __restrict__ phi,
                                                 u16* __restrict__ xT,
                                                 u16* __restrict__ Ttab) {
    __shared__ __align__(16) float xs[64][68];
    const int bid = blockIdx.x;
    const int tid = threadIdx.x;

    if (bid < 384) {
        // ---- xT: x[b][s][d] f32 -> xT[b][d][s] f16, swz (s&63)^((d&7)<<3) ----
        const int s0 = (bid & 15) << 6;
        const int d0 = ((bid >> 4) % 12) << 6;
        const int b  = bid / 192;

#pragma unroll
        for (int j = 0; j < 4; ++j) {
            int c = tid + (j << 8);
            int row = c >> 4;
            int col = (c & 15) << 2;
            *(float4*)&xs[row][col] =
                *(const float4*)&x[((size_t)b * L_SEQ + s0 + row) * D_EMB + d0 + col];
        }
        __syncthreads();

        const int dl = tid >> 2;
        const int ss = (tid & 3) << 4;
        const int dg = d0 + dl;
        const int xorv = (dg & 7) << 3;

        union { u16 v[16]; uint4 q[2]; } pk;
#pragma unroll
        for (int u = 0; u < 16; ++u)
            pk.v[u] = __half_as_ushort(__float2half(xs[ss + u][dl]));

        size_t base = (size_t)b * D_EMB * L_SEQ + (size_t)dg * L_SEQ + s0;
        *(uint4*)&xT[base + ( ss      ^ xorv)] = pk.q[0];
        *(uint4*)&xT[base + ((ss + 8) ^ xorv)] = pk.q[1];
    } else {
        // ---- Ttab[k][q]: 64x64 plus-tile, swizzled (ss ^ ((tt&7)<<3)) ----
        const int f = bid - 384;          // 0..255
        const int q = f & 15;
        const int k = f >> 4;
        const int tt  = tid >> 2;
        const int ss0 = (tid & 3) << 4;

        union { u16 v[16]; uint4 q4[2]; } pk;
#pragma unroll
        for (int u = 0; u < 16; ++u) {
            int s = (q << 6) + tt - (ss0 + u);
            float v = (s >= 0 && s < L_SEQ) ? phi[s * KF + k] : 0.f;
            pk.v[u] = __half_as_ushort(__float2half(v));
        }
        const int xorv = (tt & 7) << 3;
        u16* tile = Ttab + (((size_t)k * 16 + q) << 12);
        *(uint4*)&tile[(tt << 6) + ( ss0      ^ xorv)] = pk.q4[0];
        *(uint4*)&tile[(tt << 6) + ((ss0 + 8) ^ xorv)] = pk.q4[1];
    }
}

// =====================================================================
// Stage 1 (fused, round-19 verified ~70us): blocks 0..511 mcvt;
// blocks 512+ conv (64t x 128d, 48KB LDS -> 3 blocks/CU). dbuf +
// counted vmcnt(6). Minus sign via XOR trick; acc = 64 f32.
// =====================================================================
__global__ __launch_bounds__(256) void stu_conv_mcvt(
        const u16* __restrict__ xT, const u16* __restrict__ Ttab,
        u16* __restrict__ Up, u16* __restrict__ Um,
        const float* __restrict__ Mp, const float* __restrict__ Mm,
        u16* __restrict__ Hp, u16* __restrict__ Hm) {
    __shared__ __align__(16) u16 Xs[2][128 * 64];   // 32 KB
    __shared__ __align__(16) u16 Tps[2][64 * 64];   // 16 KB

    const int bid = blockIdx.x;
    const int tid = threadIdx.x;

    if (bid < 512) {
        // ---- mcvt: M f32 -> fp16, grid-stride over 512 blocks ----
        const size_t n8 = MELEM / 8;
        size_t i = (size_t)bid * 256 + tid;
        const size_t stride = (size_t)512 * 256;
        for (size_t cc = i; cc < n8; cc += stride) {
            const size_t g = cc << 3;
            {
                const float4 a0 = *(const float4*)&Mp[g];
                const float4 a1 = *(const float4*)&Mp[g + 4];
                union { fp16x2 h2[4]; uint4 q; } u;
                u.h2[0] = __builtin_amdgcn_cvt_pkrtz(a0.x, a0.y);
                u.h2[1] = __builtin_amdgcn_cvt_pkrtz(a0.z, a0.w);
                u.h2[2] = __builtin_amdgcn_cvt_pkrtz(a1.x, a1.y);
                u.h2[3] = __builtin_amdgcn_cvt_pkrtz(a1.z, a1.w);
                *(uint4*)&Hp[g] = u.q;
            }
            {
                const float4 a0 = *(const float4*)&Mm[g];
                const float4 a1 = *(const float4*)&Mm[g + 4];
                union { fp16x2 h2[4]; uint4 q; } u;
                u.h2[0] = __builtin_amdgcn_cvt_pkrtz(a0.x, a0.y);
                u.h2[1] = __builtin_amdgcn_cvt_pkrtz(a0.z, a0.w);
                u.h2[2] = __builtin_amdgcn_cvt_pkrtz(a1.x, a1.y);
                u.h2[3] = __builtin_amdgcn_cvt_pkrtz(a1.z, a1.w);
                *(uint4*)&Hm[g] = u.q;
            }
        }
        return;
    }

    // ---- conv block mapping: XCD-partitioned + LPT ----
    const int c    = bid - 512;          // 3072 conv blocks; xcd = c&7
    const int xcd  = c & 7;
    const int w    = c >> 3;             // 0..383 per XCD
    const int ti   = 15 - (w / 24);      // LPT: long blocks first
    const int t0   = ti << 6;
    const int inner = w % 24;            // 4 bk x 6 d-tiles
    const int bk   = (xcd << 2) + (inner / 6);    // 4 (b,k) pairs per XCD
    const int b    = bk >> 4;
    const int k    = bk & 15;
    const int d0   = (inner % 6) << 7;   // 128-wide d-tile

    const int lane = tid & 63;
    const int wid  = tid >> 6;
    const int wr   = wid >> 1;        // t-half (32 rows)
    const int wc   = wid & 1;         // d-half (64 cols)
    const int lr   = lane & 15;
    const int lk   = lane >> 4;

    // sign-trick mask: flip elements where (t+s) odd. t parity = lr parity.
    const u32 xm = (lr & 1) ? 0x00008000u : 0x80000000u;

    f32x4 acc[2][2][4];               // [sign][m][n] = 64 f32
#pragma unroll
    for (int s = 0; s < 2; ++s)
#pragma unroll
        for (int m = 0; m < 2; ++m)
#pragma unroll
            for (int n = 0; n < 4; ++n)
                acc[s][m][n] = (f32x4){0.f, 0.f, 0.f, 0.f};

    const u16* xTb = xT + (size_t)b * D_EMB * L_SEQ + (size_t)d0 * L_SEQ;
    const u16* Tpk = Ttab + ((size_t)k << 16);    // k * 16 * 4096

    auto stageX = [&](int buf, int r0) {
#pragma unroll
        for (int j = 0; j < 4; ++j) {
            int cc = tid + (j << 8);     // 1024 chunks: 128 rows x 8
            gload16(xTb + (size_t)(cc >> 3) * L_SEQ + r0 + ((cc & 7) << 3),
                    &Xs[buf][cc << 3]);
        }
    };
    auto stageT = [&](int buf, int q) {
        const u16* tp = Tpk + ((size_t)q << 12);
        gload16(tp + (tid << 3),         &Tps[buf][tid << 3]);
        gload16(tp + ((tid + 256) << 3), &Tps[buf][(tid + 256) << 3]);
    };

    stageX(0, 0);      // 4 gloads
    stageT(0, ti);     // 2 gloads  -> stage = exactly 6 vmem ops/thread

    int cur = 0;
    for (int r0 = 0; r0 <= t0; r0 += 64) {
        const int more = (r0 < t0);
        if (more) {
            stageT(cur ^ 1, ((t0 - r0) >> 6) - 1);
            stageX(cur ^ 1, r0 + 64);
        }
        if (more) { VMCNT6(); } else { VMCNT0(); }
        __builtin_amdgcn_s_barrier();

        const char* XsC = (const char*)&Xs[cur][0];
        const char* TpC = (const char*)&Tps[cur][0];

#pragma unroll
        for (int kk = 0; kk < 2; ++kk) {
            f16x8 bfr[4];
#pragma unroll
            for (int n = 0; n < 4; ++n) {
                const int row = (wc << 6) + (n << 4) + lr;
                const int boff = ((kk << 6) + (lk << 4)) ^ ((row & 7) << 4);
                bfr[n] = *(const f16x8*)(XsC + row * 128 + boff);
            }
#pragma unroll
            for (int m = 0; m < 2; ++m) {
                const int rowt = (wr << 5) + (m << 4) + lr;
                const int aoff = ((kk << 6) + (lk << 4)) ^ ((rowt & 7) << 4);
                const f16x8 ap = *(const f16x8*)(TpC + rowt * 128 + aoff);
                union { f16x8 h; u32 wv[4]; } cv;
                cv.h = ap;
#pragma unroll
                for (int qd = 0; qd < 4; ++qd) cv.wv[qd] ^= xm;
                const f16x8 am = cv.h;
#pragma unroll
                for (int n = 0; n < 4; ++n) {
                    acc[0][m][n] = __builtin_amdgcn_mfma_f32_16x16x32_f16(
                        ap, bfr[n], acc[0][m][n], 0, 0, 0);
                    acc[1][m][n] = __builtin_amdgcn_mfma_f32_16x16x32_f16(
                        am, bfr[n], acc[1][m][n], 0, 0, 0);
                }
            }
        }
        __builtin_amdgcn_s_barrier();
        cur ^= 1;
    }

    // epilogue: t row = m*16 + lk*4 + j, d col = n*16 + lr
#pragma unroll
    for (int m = 0; m < 2; ++m) {
        const int trow = t0 + (wr << 5) + (m << 4) + (lk << 2);
#pragma unroll
        for (int n = 0; n < 4; ++n) {
            const int col = d0 + (wc << 6) + (n << 4) + lr;
#pragma unroll
            for (int j = 0; j < 4; ++j) {
                size_t idx = ((size_t)(b * L_SEQ + trow + j) * KF + k) * D_EMB + col;
                Up[idx] = __half_as_ushort(__float2half(acc[0][m][n][j]));
                Um[idx] = __half_as_ushort(__float2half(acc[1][m][n][j]));
            }
        }
    }
}

// =====================================================================
// Stage 2 (MFMA): m-split for occupancy — block = 64m x 128o (was 128m),
// LDS 24KB, grid 32x6x8 = 1536 blocks = 6/CU (was 3). BK=64, 8-chunk
// XOR swizzle, split-K fp16 partials (same total Part size).
// =====================================================================
__global__ __launch_bounds__(256) void stu_spectral_mfma(
        const u16* __restrict__ Up, const u16* __restrict__ Um,
        const u16* __restrict__ Mhp, const u16* __restrict__ Mhm,
        float* __restrict__ out, u16* __restrict__ P, int usePartial) {
    __shared__ __align__(16) u16 As[64 * 64];    // 8 KB
    __shared__ __align__(16) u16 Bs[128 * 64];   // 16 KB

    const int h   = blockIdx.x;                   // 0..1535
    const int z   = h & 7;                        // XCD slice
    const int rem = h >> 3;                       // 0..191
    const int o0  = (rem % 6) << 7;
    const int m0  = (rem / 6) << 6;               // 64-row m-tile
    const int sign = z & 1;
    const int k0 = (z >> 1) << 2;

    const u16* A    = sign ? Um : Up;
    const u16* Bsrc = sign ? Mhm : Mhp;

    const int tid  = threadIdx.x;
    const int lane = tid & 63;
    const int wid  = tid >> 6;                    // 0..3 : o-quarter
    const int lr   = lane & 15;
    const int lk   = lane >> 4;

    f32x4 acc[4][2];                              // 64m x 32o per wave
#pragma unroll
    for (int m = 0; m < 4; ++m)
#pragma unroll
        for (int n = 0; n < 2; ++n)
            acc[m][n] = (f32x4){0.f, 0.f, 0.f, 0.f};

    for (int k = k0; k < k0 + 4; ++k) {
        const u16* Ak = A + (size_t)m0 * KROW + k * D_EMB;
        const u16* Bk = Bsrc + (size_t)k * D_EMB * D_EMB + (size_t)o0 * D_EMB;

        for (int ic = 0; ic < D_EMB; ic += 64) {
            __syncthreads();
            // A: 64 rows x 8 chunks = 512 -> 2/thread
#pragma unroll
            for (int j = 0; j < 2; ++j) {
                const int c = tid + (j << 8);
                const int row = c >> 3;
                const int off = ((c & 7) ^ (row & 7)) << 3;
                gload16(Ak + (size_t)row * KROW + ic + off, &As[c << 3]);
            }
            // B: 128 rows x 8 chunks = 1024 -> 4/thread
#pragma unroll
            for (int j = 0; j < 4; ++j) {
                const int c = tid + (j << 8);
                const int row = c >> 3;
                const int off = ((c & 7) ^ (row & 7)) << 3;
                gload16(Bk + (size_t)row * D_EMB + ic + off, &Bs[c << 3]);
            }
            __syncthreads();

#pragma unroll
            for (int kk = 0; kk < 2; ++kk) {
                f16x8 af[4], bf[2];
#pragma unroll
                for (int m = 0; m < 4; ++m) {
                    const int row = (m << 4) + lr;
                    const int boff = (((kk << 2) + lk) ^ (row & 7)) << 4;
                    af[m] = *(const f16x8*)((const char*)&As[0] + row * 128 + boff);
                }
#pragma unroll
                for (int n = 0; n < 2; ++n) {
                    const int row = (wid << 5) + (n << 4) + lr;
                    const int boff = (((kk << 2) + lk) ^ (row & 7)) << 4;
                    bf[n] = *(const f16x8*)((const char*)&Bs[0] + row * 128 + boff);
                }
#pragma unroll
                for (int m = 0; m < 4; ++m)
#pragma unroll
                    for (int n = 0; n < 2; ++n)
                        acc[m][n] = __builtin_amdgcn_mfma_f32_16x16x32_f16(
                            af[m], bf[n], acc[m][n], 0, 0, 0);
            }
        }
    }

    if (usePartial) {
        u16* Pt = P + (size_t)h * PT2;            // 64x128 tile
#pragma unroll
        for (int m = 0; m < 4; ++m) {
            const int rowl = (m << 4) + (lk << 2);
#pragma unroll
            for (int n = 0; n < 2; ++n) {
                const int coll = (wid << 5) + (n << 4) + lr;
#pragma unroll
                for (int j = 0; j < 4; ++j)
                    Pt[(rowl + j) * 128 + coll] =
                        __half_as_ushort(__float2half(acc[m][n][j]));
            }
        }
    } else {
#pragma unroll
        for (int m = 0; m < 4; ++m) {
            const int row = m0 + (m << 4) + (lk << 2);
#pragma unroll
            for (int n = 0; n < 2; ++n) {
                const int col = o0 + (wid << 5) + (n << 4) + lr;
#pragma unroll
                for (int j = 0; j < 4; ++j)
                    atomicAdd(&out[(size_t)(row + j) * D_EMB + col], acc[m][n][j]);
            }
        }
    }
}

// =====================================================================
// Reduce (vectorized): one thread per 8 contiguous cols; partial tiles
// are 64m x 128o, 8 z-partials contiguous at stride PT2 per (m,o) tile.
// =====================================================================
__global__ __launch_bounds__(256) void stu_reduce(const u16* __restrict__ P,
                                                  float* __restrict__ out) {
    const int g    = blockIdx.x * 256 + threadIdx.x;   // 0..196607
    const int row  = g / 96;
    const int col0 = (g % 96) << 3;
    const int tile = (row >> 6) * 6 + (col0 >> 7);
    const u16* p = P + (size_t)tile * 8 * PT2 + ((row & 63) << 7) + (col0 & 127);

    float s[8] = {0.f, 0.f, 0.f, 0.f, 0.f, 0.f, 0.f, 0.f};
#pragma unroll
    for (int z = 0; z < 8; ++z) {
        const uint4 q = *(const uint4*)(p + (size_t)z * PT2);
        union { uint4 q; u16 v[8]; } u;
        u.q = q;
#pragma unroll
        for (int j = 0; j < 8; ++j)
            s[j] += __half2float(__ushort_as_half(u.v[j]));
    }
    const size_t ob = (size_t)row * D_EMB + col0;
    *(float4*)&out[ob]     = (float4){s[0], s[1], s[2], s[3]};
    *(float4*)&out[ob + 4] = (float4){s[4], s[5], s[6], s[7]};
}

extern "C" void kernel_launch(void* const* d_in, const int* in_sizes, int n_in,
                              void* d_out, int out_size, void* d_ws, size_t ws_size,
                              hipStream_t stream) {
    const float* x   = (const float*)d_in[0];
    const float* phi = (const float*)d_in[1];
    const float* Mp  = (const float*)d_in[2];
    const float* Mm  = (const float*)d_in[3];
    float* out = (float*)d_out;

    const size_t S = (size_t)MDIM * KROW;            // 25,165,824
    u16* Up   = (u16*)d_ws;
    u16* Um   = Up + S;
    u16* Mhp  = Um + S;
    u16* Mhm  = Mhp + MELEM;
    u16* xT   = Mhm + MELEM;                         // 1,572,864
    u16* Ttab = xT + (size_t)B_SZ * D_EMB * L_SEQ;   // 1,048,576 (plus-only)
    u16* Part = Ttab + (size_t)KF * 16 * 4096;       // 1536*8192 = 12,582,912

    const size_t elems_needed = 2 * S + 2 * MELEM + 1572864 + 1048576 + 12582912;
    const int usePartial = (ws_size >= elems_needed * sizeof(u16)) ? 1 : 0;

    if (!usePartial)
        (void)hipMemsetAsync(d_out, 0, (size_t)out_size * sizeof(float), stream);

    stu_setup<<<dim3(640), dim3(256), 0, stream>>>(x, phi, xT, Ttab);

    // 512 mcvt blocks (overlap) + 3072 conv blocks (XCD-partitioned, 128d)
    stu_conv_mcvt<<<dim3(3584), dim3(256), 0, stream>>>(
        xT, Ttab, Up, Um, Mp, Mm, Mhp, Mhm);

    stu_spectral_mfma<<<dim3(1536), dim3(256), 0, stream>>>(
        Up, Um, Mhp, Mhm, out, Part, usePartial);

    if (usePartial)
        stu_reduce<<<dim3(768), dim3(256), 0, stream>>>(Part, out);
}

// Round 21
// 163.556 us; speedup vs baseline: 1.0866x; 1.0866x over previous
//
#include <hip/hip_runtime.h>
#include <hip/hip_fp16.h>

typedef unsigned short u16;
typedef unsigned int   u32;
typedef _Float16 f16;
typedef __attribute__((ext_vector_type(8))) f16 f16x8;
typedef __attribute__((ext_vector_type(2))) __fp16 fp16x2;   // cvt_pkrtz return type
typedef __attribute__((ext_vector_type(4))) float f32x4;

#define B_SZ  2
#define L_SEQ 1024
#define D_EMB 768
#define KF    16
#define MDIM  (B_SZ * L_SEQ)   // 2048 GEMM rows
#define KROW  (KF * D_EMB)     // 12288 per-row A length
#define MELEM ((size_t)KF * D_EMB * D_EMB)   // 9,437,184 per M matrix
#define NTILE 96                // 16 m-tiles x 6 o-tiles
#define PT_SZ 16384             // 128x128 partial tile elems

// ---- async global->LDS, 16B per lane (linear LDS dest: wave base + lane*16) ----
__device__ __forceinline__ void gload16(const void* g, void* l) {
    __builtin_amdgcn_global_load_lds(
        (const __attribute__((address_space(1))) u32*)g,
        (__attribute__((address_space(3))) u32*)l, 16, 0, 0);
}

// counted vmcnt waits (T4): literal-only, memory-clobbered so staging/ds ops
// cannot be reordered across them by the compiler.
#define VMCNT6() asm volatile("s_waitcnt vmcnt(6)" ::: "memory")
#define VMCNT0() asm volatile("s_waitcnt vmcnt(0)" ::: "memory")

// =====================================================================
// Setup (fused, round-13 verified): blocks 0..383 transpose x -> xT
// (pre-swizzled); blocks 384..639 build the PLUS-ONLY Toeplitz tile
// table (64x64 tiles, pre-swizzled).
// =====================================================================
__global__ __launch_bounds__(256) void stu_setup(const float* __restrict__ x,
                                                 const float* __restrict__ phi,
                                                 u16* __restrict__ xT,
                                                 u16* __restrict__ Ttab) {
    __shared__ __align__(16) float xs[64][68];
    const int bid = blockIdx.x;
    const int tid = threadIdx.x;

    if (bid < 384) {
        // ---- xT: x[b][s][d] f32 -> xT[b][d][s] f16, swz (s&63)^((d&7)<<3) ----
        const int s0 = (bid & 15) << 6;
        const int d0 = ((bid >> 4) % 12) << 6;
        const int b  = bid / 192;

#pragma unroll
        for (int j = 0; j < 4; ++j) {
            int c = tid + (j << 8);
            int row = c >> 4;
            int col = (c & 15) << 2;
            *(float4*)&xs[row][col] =
                *(const float4*)&x[((size_t)b * L_SEQ + s0 + row) * D_EMB + d0 + col];
        }
        __syncthreads();

        const int dl = tid >> 2;
        const int ss = (tid & 3) << 4;
        const int dg = d0 + dl;
        const int xorv = (dg & 7) << 3;

        union { u16 v[16]; uint4 q[2]; } pk;
#pragma unroll
        for (int u = 0; u < 16; ++u)
            pk.v[u] = __half_as_ushort(__float2half(xs[ss + u][dl]));

        size_t base = (size_t)b * D_EMB * L_SEQ + (size_t)dg * L_SEQ + s0;
        *(uint4*)&xT[base + ( ss      ^ xorv)] = pk.q[0];
        *(uint4*)&xT[base + ((ss + 8) ^ xorv)] = pk.q[1];
    } else {
        // ---- Ttab[k][q]: 64x64 plus-tile, swizzled (ss ^ ((tt&7)<<3)) ----
        const int f = bid - 384;          // 0..255
        const int q = f & 15;
        const int k = f >> 4;
        const int tt  = tid >> 2;
        const int ss0 = (tid & 3) << 4;

        union { u16 v[16]; uint4 q4[2]; } pk;
#pragma unroll
        for (int u = 0; u < 16; ++u) {
            int s = (q << 6) + tt - (ss0 + u);
            float v = (s >= 0 && s < L_SEQ) ? phi[s * KF + k] : 0.f;
            pk.v[u] = __half_as_ushort(__float2half(v));
        }
        const int xorv = (tt & 7) << 3;
        u16* tile = Ttab + (((size_t)k * 16 + q) << 12);
        *(uint4*)&tile[(tt << 6) + ( ss0      ^ xorv)] = pk.q4[0];
        *(uint4*)&tile[(tt << 6) + ((ss0 + 8) ^ xorv)] = pk.q4[1];
    }
}

// =====================================================================
// Stage 1 (fused, round-19 verified ~70us): blocks 0..511 mcvt;
// blocks 512+ conv (64t x 128d, 48KB LDS -> 3 blocks/CU). dbuf +
// counted vmcnt(6). Minus sign via XOR trick; acc = 64 f32.
// =====================================================================
__global__ __launch_bounds__(256) void stu_conv_mcvt(
        const u16* __restrict__ xT, const u16* __restrict__ Ttab,
        u16* __restrict__ Up, u16* __restrict__ Um,
        const float* __restrict__ Mp, const float* __restrict__ Mm,
        u16* __restrict__ Hp, u16* __restrict__ Hm) {
    __shared__ __align__(16) u16 Xs[2][128 * 64];   // 32 KB
    __shared__ __align__(16) u16 Tps[2][64 * 64];   // 16 KB

    const int bid = blockIdx.x;
    const int tid = threadIdx.x;

    if (bid < 512) {
        // ---- mcvt: M f32 -> fp16, grid-stride over 512 blocks ----
        const size_t n8 = MELEM / 8;
        size_t i = (size_t)bid * 256 + tid;
        const size_t stride = (size_t)512 * 256;
        for (size_t cc = i; cc < n8; cc += stride) {
            const size_t g = cc << 3;
            {
                const float4 a0 = *(const float4*)&Mp[g];
                const float4 a1 = *(const float4*)&Mp[g + 4];
                union { fp16x2 h2[4]; uint4 q; } u;
                u.h2[0] = __builtin_amdgcn_cvt_pkrtz(a0.x, a0.y);
                u.h2[1] = __builtin_amdgcn_cvt_pkrtz(a0.z, a0.w);
                u.h2[2] = __builtin_amdgcn_cvt_pkrtz(a1.x, a1.y);
                u.h2[3] = __builtin_amdgcn_cvt_pkrtz(a1.z, a1.w);
                *(uint4*)&Hp[g] = u.q;
            }
            {
                const float4 a0 = *(const float4*)&Mm[g];
                const float4 a1 = *(const float4*)&Mm[g + 4];
                union { fp16x2 h2[4]; uint4 q; } u;
                u.h2[0] = __builtin_amdgcn_cvt_pkrtz(a0.x, a0.y);
                u.h2[1] = __builtin_amdgcn_cvt_pkrtz(a0.z, a0.w);
                u.h2[2] = __builtin_amdgcn_cvt_pkrtz(a1.x, a1.y);
                u.h2[3] = __builtin_amdgcn_cvt_pkrtz(a1.z, a1.w);
                *(uint4*)&Hm[g] = u.q;
            }
        }
        return;
    }

    // ---- conv block mapping: XCD-partitioned + LPT ----
    const int c    = bid - 512;          // 3072 conv blocks; xcd = c&7
    const int xcd  = c & 7;
    const int w    = c >> 3;             // 0..383 per XCD
    const int ti   = 15 - (w / 24);      // LPT: long blocks first
    const int t0   = ti << 6;
    const int inner = w % 24;            // 4 bk x 6 d-tiles
    const int bk   = (xcd << 2) + (inner / 6);    // 4 (b,k) pairs per XCD
    const int b    = bk >> 4;
    const int k    = bk & 15;
    const int d0   = (inner % 6) << 7;   // 128-wide d-tile

    const int lane = tid & 63;
    const int wid  = tid >> 6;
    const int wr   = wid >> 1;        // t-half (32 rows)
    const int wc   = wid & 1;         // d-half (64 cols)
    const int lr   = lane & 15;
    const int lk   = lane >> 4;

    // sign-trick mask: flip elements where (t+s) odd. t parity = lr parity.
    const u32 xm = (lr & 1) ? 0x00008000u : 0x80000000u;

    f32x4 acc[2][2][4];               // [sign][m][n] = 64 f32
#pragma unroll
    for (int s = 0; s < 2; ++s)
#pragma unroll
        for (int m = 0; m < 2; ++m)
#pragma unroll
            for (int n = 0; n < 4; ++n)
                acc[s][m][n] = (f32x4){0.f, 0.f, 0.f, 0.f};

    const u16* xTb = xT + (size_t)b * D_EMB * L_SEQ + (size_t)d0 * L_SEQ;
    const u16* Tpk = Ttab + ((size_t)k << 16);    // k * 16 * 4096

    auto stageX = [&](int buf, int r0) {
#pragma unroll
        for (int j = 0; j < 4; ++j) {
            int cc = tid + (j << 8);     // 1024 chunks: 128 rows x 8
            gload16(xTb + (size_t)(cc >> 3) * L_SEQ + r0 + ((cc & 7) << 3),
                    &Xs[buf][cc << 3]);
        }
    };
    auto stageT = [&](int buf, int q) {
        const u16* tp = Tpk + ((size_t)q << 12);
        gload16(tp + (tid << 3),         &Tps[buf][tid << 3]);
        gload16(tp + ((tid + 256) << 3), &Tps[buf][(tid + 256) << 3]);
    };

    stageX(0, 0);      // 4 gloads
    stageT(0, ti);     // 2 gloads  -> stage = exactly 6 vmem ops/thread

    int cur = 0;
    for (int r0 = 0; r0 <= t0; r0 += 64) {
        const int more = (r0 < t0);
        if (more) {
            stageT(cur ^ 1, ((t0 - r0) >> 6) - 1);
            stageX(cur ^ 1, r0 + 64);
        }
        if (more) { VMCNT6(); } else { VMCNT0(); }
        __builtin_amdgcn_s_barrier();

        const char* XsC = (const char*)&Xs[cur][0];
        const char* TpC = (const char*)&Tps[cur][0];

#pragma unroll
        for (int kk = 0; kk < 2; ++kk) {
            f16x8 bfr[4];
#pragma unroll
            for (int n = 0; n < 4; ++n) {
                const int row = (wc << 6) + (n << 4) + lr;
                const int boff = ((kk << 6) + (lk << 4)) ^ ((row & 7) << 4);
                bfr[n] = *(const f16x8*)(XsC + row * 128 + boff);
            }
#pragma unroll
            for (int m = 0; m < 2; ++m) {
                const int rowt = (wr << 5) + (m << 4) + lr;
                const int aoff = ((kk << 6) + (lk << 4)) ^ ((rowt & 7) << 4);
                const f16x8 ap = *(const f16x8*)(TpC + rowt * 128 + aoff);
                union { f16x8 h; u32 wv[4]; } cv;
                cv.h = ap;
#pragma unroll
                for (int qd = 0; qd < 4; ++qd) cv.wv[qd] ^= xm;
                const f16x8 am = cv.h;
#pragma unroll
                for (int n = 0; n < 4; ++n) {
                    acc[0][m][n] = __builtin_amdgcn_mfma_f32_16x16x32_f16(
                        ap, bfr[n], acc[0][m][n], 0, 0, 0);
                    acc[1][m][n] = __builtin_amdgcn_mfma_f32_16x16x32_f16(
                        am, bfr[n], acc[1][m][n], 0, 0, 0);
                }
            }
        }
        __builtin_amdgcn_s_barrier();
        cur ^= 1;
    }

    // epilogue: t row = m*16 + lk*4 + j, d col = n*16 + lr
#pragma unroll
    for (int m = 0; m < 2; ++m) {
        const int trow = t0 + (wr << 5) + (m << 4) + (lk << 2);
#pragma unroll
        for (int n = 0; n < 4; ++n) {
            const int col = d0 + (wc << 6) + (n << 4) + lr;
#pragma unroll
            for (int j = 0; j < 4; ++j) {
                size_t idx = ((size_t)(b * L_SEQ + trow + j) * KF + k) * D_EMB + col;
                Up[idx] = __half_as_ushort(__float2half(acc[0][m][n][j]));
                Um[idx] = __half_as_ushort(__float2half(acc[1][m][n][j]));
            }
        }
    }
}

// =====================================================================
// Stage 2 (MFMA, round-19 verified ~83us @ MfmaUtil 41%): 128m x 128o,
// BK=64, 8-chunk XOR swizzle, split-K fp16 partials, single-buffered
// 32KB, 768 blocks XCD-partitioned (3/CU — ratio/occupancy optimum).
// =====================================================================
__global__ __launch_bounds__(256) void stu_spectral_mfma(
        const u16* __restrict__ Up, const u16* __restrict__ Um,
        const u16* __restrict__ Mhp, const u16* __restrict__ Mhm,
        float* __restrict__ out, u16* __restrict__ P, int usePartial) {
    __shared__ __align__(16) u16 As[128 * 64];   // 16 KB
    __shared__ __align__(16) u16 Bs[128 * 64];   // 16 KB

    const int h   = blockIdx.x;
    const int z   = h & 7;                        // XCD slice
    const int rem = h >> 3;                       // 0..95
    const int o0  = (rem % 6) << 7;
    const int m0  = (rem / 6) << 7;
    const int sign = z & 1;
    const int k0 = (z >> 1) << 2;

    const u16* A    = sign ? Um : Up;
    const u16* Bsrc = sign ? Mhm : Mhp;

    const int tid  = threadIdx.x;
    const int lane = tid & 63;
    const int wid  = tid >> 6;
    const int wr   = wid >> 1;
    const int wc   = wid & 1;
    const int lr   = lane & 15;
    const int lk   = lane >> 4;

    f32x4 acc[4][4];
#pragma unroll
    for (int m = 0; m < 4; ++m)
#pragma unroll
        for (int n = 0; n < 4; ++n)
            acc[m][n] = (f32x4){0.f, 0.f, 0.f, 0.f};

    for (int k = k0; k < k0 + 4; ++k) {
        const u16* Ak = A + (size_t)m0 * KROW + k * D_EMB;
        const u16* Bk = Bsrc + (size_t)k * D_EMB * D_EMB + (size_t)o0 * D_EMB;

        for (int ic = 0; ic < D_EMB; ic += 64) {
            __syncthreads();
#pragma unroll
            for (int j = 0; j < 4; ++j) {
                const int c = tid + (j << 8);
                const int row = c >> 3;
                const int off = ((c & 7) ^ (row & 7)) << 3;
                gload16(Ak + (size_t)row * KROW + ic + off, &As[c << 3]);
                gload16(Bk + (size_t)row * D_EMB + ic + off, &Bs[c << 3]);
            }
            __syncthreads();

#pragma unroll
            for (int kk = 0; kk < 2; ++kk) {
                f16x8 af[4], bf[4];
#pragma unroll
                for (int m = 0; m < 4; ++m) {
                    const int row = wr * 64 + (m << 4) + lr;
                    const int boff = (((kk << 2) + lk) ^ (row & 7)) << 4;
                    af[m] = *(const f16x8*)((const char*)&As[0] + row * 128 + boff);
                }
#pragma unroll
                for (int n = 0; n < 4; ++n) {
                    const int row = wc * 64 + (n << 4) + lr;
                    const int boff = (((kk << 2) + lk) ^ (row & 7)) << 4;
                    bf[n] = *(const f16x8*)((const char*)&Bs[0] + row * 128 + boff);
                }
#pragma unroll
                for (int m = 0; m < 4; ++m)
#pragma unroll
                    for (int n = 0; n < 4; ++n)
                        acc[m][n] = __builtin_amdgcn_mfma_f32_16x16x32_f16(
                            af[m], bf[n], acc[m][n], 0, 0, 0);
            }
        }
    }

    if (usePartial) {
        u16* Pt = P + (size_t)h * PT_SZ;
#pragma unroll
        for (int m = 0; m < 4; ++m) {
            const int rowl = wr * 64 + (m << 4) + (lk << 2);
#pragma unroll
            for (int n = 0; n < 4; ++n) {
                const int coll = wc * 64 + (n << 4) + lr;
#pragma unroll
                for (int j = 0; j < 4; ++j)
                    Pt[(rowl + j) * 128 + coll] =
                        __half_as_ushort(__float2half(acc[m][n][j]));
            }
        }
    } else {
#pragma unroll
        for (int m = 0; m < 4; ++m) {
            const int row = m0 + wr * 64 + (m << 4) + (lk << 2);
#pragma unroll
            for (int n = 0; n < 4; ++n) {
                const int col = o0 + wc * 64 + (n << 4) + lr;
#pragma unroll
                for (int j = 0; j < 4; ++j)
                    atomicAdd(&out[(size_t)(row + j) * D_EMB + col], acc[m][n][j]);
            }
        }
    }
}

// =====================================================================
// Reduce (vectorized, round-16 verified): one thread per 8 contiguous
// cols; 8x uint4 loads + 2x float4 store. Exact-fit grid.
// =====================================================================
__global__ __launch_bounds__(256) void stu_reduce(const u16* __restrict__ P,
                                                  float* __restrict__ out) {
    const int g    = blockIdx.x * 256 + threadIdx.x;   // 0..196607
    const int row  = g / 96;
    const int col0 = (g % 96) << 3;
    const int tile = (row >> 7) * 6 + (col0 >> 7);
    const u16* p = P + (size_t)tile * 8 * PT_SZ + ((row & 127) << 7) + (col0 & 127);

    float s[8] = {0.f, 0.f, 0.f, 0.f, 0.f, 0.f, 0.f, 0.f};
#pragma unroll
    for (int z = 0; z < 8; ++z) {
        const uint4 q = *(const uint4*)(p + (size_t)z * PT_SZ);
        union { uint4 q; u16 v[8]; } u;
        u.q = q;
#pragma unroll
        for (int j = 0; j < 8; ++j)
            s[j] += __half2float(__ushort_as_half(u.v[j]));
    }
    const size_t ob = (size_t)row * D_EMB + col0;
    *(float4*)&out[ob]     = (float4){s[0], s[1], s[2], s[3]};
    *(float4*)&out[ob + 4] = (float4){s[4], s[5], s[6], s[7]};
}

extern "C" void kernel_launch(void* const* d_in, const int* in_sizes, int n_in,
                              void* d_out, int out_size, void* d_ws, size_t ws_size,
                              hipStream_t stream) {
    const float* x   = (const float*)d_in[0];
    const float* phi = (const float*)d_in[1];
    const float* Mp  = (const float*)d_in[2];
    const float* Mm  = (const float*)d_in[3];
    float* out = (float*)d_out;

    const size_t S = (size_t)MDIM * KROW;            // 25,165,824
    u16* Up   = (u16*)d_ws;
    u16* Um   = Up + S;
    u16* Mhp  = Um + S;
    u16* Mhm  = Mhp + MELEM;
    u16* xT   = Mhm + MELEM;                         // 1,572,864
    u16* Ttab = xT + (size_t)B_SZ * D_EMB * L_SEQ;   // 1,048,576 (plus-only)
    u16* Part = Ttab + (size_t)KF * 16 * 4096;       // 12,582,912 (25.2 MB)

    const size_t elems_needed = 2 * S + 2 * MELEM + 1572864 + 1048576 + 12582912;
    const int usePartial = (ws_size >= elems_needed * sizeof(u16)) ? 1 : 0;

    if (!usePartial)
        (void)hipMemsetAsync(d_out, 0, (size_t)out_size * sizeof(float), stream);

    stu_setup<<<dim3(640), dim3(256), 0, stream>>>(x, phi, xT, Ttab);

    // 512 mcvt blocks (overlap) + 3072 conv blocks (XCD-partitioned, 128d)
    stu_conv_mcvt<<<dim3(3584), dim3(256), 0, stream>>>(
        xT, Ttab, Up, Um, Mp, Mm, Mhp, Mhm);

    stu_spectral_mfma<<<dim3(NTILE * 8), dim3(256), 0, stream>>>(
        Up, Um, Mhp, Mhm, out, Part, usePartial);

    if (usePartial)
        stu_reduce<<<dim3(768), dim3(256), 0, stream>>>(Part, out);
}